// Round 1
// baseline (3946.435 us; speedup 1.0000x reference)
//
#include <hip/hip_runtime.h>
#include <math.h>

#define HIDDEN 512
#define WINDOW 24
#define KSZ 3
#define BATCH 2048
#define L_IN (HIDDEN + KSZ - 1)   // 514
#define H4 (4 * HIDDEN)           // 2048

// ---------------------------------------------------------------------------
// Shared fp32 GEMM core: C[m0+.., n0+..] (+)= A[m,:K] . B[n,:K]  (A @ B^T)
// 64x64 tile, BK=16, 256 threads, 4x4 micro-tile per thread.
// As/Bs stored transposed [k][m] so compute reads are ds_read_b128.
// ---------------------------------------------------------------------------
__device__ __forceinline__ void gemm_tile(const float* __restrict__ A, int lda,
                                          const float* __restrict__ B, int ldb,
                                          int K, float (&acc)[4][4],
                                          float (&As)[16][64], float (&Bs)[16][64],
                                          int m0, int n0, int tid) {
    const int lm = tid >> 2;            // 0..63
    const int lk = (tid & 3) << 2;      // 0,4,8,12
    const int ty = tid >> 4;            // 0..15 (m)
    const int tx = tid & 15;            // 0..15 (n)
    for (int k0 = 0; k0 < K; k0 += 16) {
        float4 av = *(const float4*)(A + (size_t)(m0 + lm) * lda + k0 + lk);
        float4 bv = *(const float4*)(B + (size_t)(n0 + lm) * ldb + k0 + lk);
        As[lk + 0][lm] = av.x; As[lk + 1][lm] = av.y;
        As[lk + 2][lm] = av.z; As[lk + 3][lm] = av.w;
        Bs[lk + 0][lm] = bv.x; Bs[lk + 1][lm] = bv.y;
        Bs[lk + 2][lm] = bv.z; Bs[lk + 3][lm] = bv.w;
        __syncthreads();
#pragma unroll
        for (int k = 0; k < 16; ++k) {
            const float4 a4 = *(const float4*)&As[k][ty << 2];
            const float4 b4 = *(const float4*)&Bs[k][tx << 2];
            const float a[4] = {a4.x, a4.y, a4.z, a4.w};
            const float b[4] = {b4.x, b4.y, b4.z, b4.w};
#pragma unroll
            for (int r = 0; r < 4; ++r)
#pragma unroll
                for (int c = 0; c < 4; ++c) acc[r][c] += a[r] * b[c];
        }
        __syncthreads();
    }
}

// ---------------------------------------------------------------------------
// K0: conv1d(2->24, k=3, valid) + bias + relu.  Ht[t][b][i] layout.
// ---------------------------------------------------------------------------
__global__ void conv_kernel(const float* __restrict__ Z, const float* __restrict__ conv_w,
                            const float* __restrict__ conv_b, float* __restrict__ Ht) {
    __shared__ float cw[WINDOW * 2 * KSZ];
    __shared__ float cb[WINDOW];
    const int b = blockIdx.x;
    if (threadIdx.x < WINDOW * 2 * KSZ) cw[threadIdx.x] = conv_w[threadIdx.x];
    if (threadIdx.x < WINDOW) cb[threadIdx.x] = conv_b[threadIdx.x];
    __syncthreads();
    const float* z0 = Z + (size_t)b * L_IN;                          // Z[0][b][:]
    const float* z1 = Z + (size_t)BATCH * L_IN + (size_t)b * L_IN;   // Z[1][b][:]
    for (int i = threadIdx.x; i < HIDDEN; i += blockDim.x) {
        const float a0 = z0[i], a1 = z0[i + 1], a2 = z0[i + 2];
        const float b0 = z1[i], b1 = z1[i + 1], b2 = z1[i + 2];
#pragma unroll
        for (int o = 0; o < WINDOW; ++o) {
            const float* wc = cw + o * 6;
            float v = cb[o] + a0 * wc[0] + a1 * wc[1] + a2 * wc[2]
                            + b0 * wc[3] + b1 * wc[4] + b2 * wc[5];
            Ht[((size_t)o * BATCH + b) * HIDDEN + i] = fmaxf(v, 0.f);
        }
    }
}

// ---------------------------------------------------------------------------
// K1: G = Ht_flat[49152 x 512] @ Ud^T   (state independent, hoisted)
// ---------------------------------------------------------------------------
__global__ __launch_bounds__(256) void g_gemm_kernel(const float* __restrict__ Ht,
                                                     const float* __restrict__ Ud,
                                                     float* __restrict__ G) {
    __shared__ float As[16][64];
    __shared__ float Bs[16][64];
    float acc[4][4] = {};
    const int tid = threadIdx.x;
    const int m0 = blockIdx.x * 64, n0 = blockIdx.y * 64;
    gemm_tile(Ht, HIDDEN, Ud, HIDDEN, HIDDEN, acc, As, Bs, m0, n0, tid);
    const int ty = tid >> 4, tx = tid & 15;
#pragma unroll
    for (int r = 0; r < 4; ++r) {
        const int m = m0 + (ty << 2) + r;
        float4 v = make_float4(acc[r][0], acc[r][1], acc[r][2], acc[r][3]);
        *(float4*)&G[(size_t)m * HIDDEN + n0 + (tx << 2)] = v;
    }
}

// ---------------------------------------------------------------------------
// init: yr_dot[b] = y_real[b,:24] . w[:24];  ct_row = 0
// ---------------------------------------------------------------------------
__global__ void init_kernel(const float* __restrict__ y_real, const float* __restrict__ w,
                            float* __restrict__ yr_dot, float* __restrict__ ct_row) {
    const int tid = blockIdx.x * blockDim.x + threadIdx.x;
    if (tid < BATCH) {
        float s = 0.f;
#pragma unroll
        for (int j = 0; j < WINDOW; ++j) s += y_real[tid * WINDOW + j] * w[j];
        yr_dot[tid] = s;
    }
    if (tid < HIDDEN) ct_row[tid] = 0.f;
}

// ---------------------------------------------------------------------------
// S1: lpart[nblk][b] = sum_i tanh(d0@WdA^T + s0@WdB^T + G_t)[b,i] * vd[i]
// ---------------------------------------------------------------------------
__global__ __launch_bounds__(256) void s1_kernel(const float* __restrict__ d0,
                                                 const float* __restrict__ s0,
                                                 const float* __restrict__ Wd,
                                                 const float* __restrict__ Gt,
                                                 const float* __restrict__ vd,
                                                 float* __restrict__ lpart) {
    __shared__ float As[16][64];
    __shared__ float Bs[16][64];
    float acc[4][4] = {};
    const int tid = threadIdx.x;
    const int m0 = blockIdx.x * 64, n0 = blockIdx.y * 64;
    // ds = [d0, s0]: k<512 -> d0 with Wd cols [0,512); k>=512 -> s0 with Wd cols [512,1024)
    gemm_tile(d0, HIDDEN, Wd,       2 * HIDDEN, HIDDEN, acc, As, Bs, m0, n0, tid);
    gemm_tile(s0, HIDDEN, Wd + 512, 2 * HIDDEN, HIDDEN, acc, As, Bs, m0, n0, tid);
    const int ty = tid >> 4, tx = tid & 15;
#pragma unroll
    for (int r = 0; r < 4; ++r) {
        const int b = m0 + (ty << 2) + r;
        float s = 0.f;
#pragma unroll
        for (int c = 0; c < 4; ++c) {
            const int i = n0 + (tx << 2) + c;
            s += tanhf(acc[r][c] + Gt[(size_t)b * HIDDEN + i]) * vd[i];
        }
        // reduce across the 16 tx lanes (lanes 0..15 of each 16-group)
        for (int m = 8; m; m >>= 1) s += __shfl_xor(s, m, 16);
        if (tx == 0) lpart[(size_t)blockIdx.y * BATCH + b] = s;
    }
}

// ---------------------------------------------------------------------------
// S2: softmax over batch (2048), summing 8 column-block partials first
// ---------------------------------------------------------------------------
__global__ void softmax_kernel(const float* __restrict__ lpart, float* __restrict__ Bw) {
    __shared__ float sm[1024];
    const int tid = threadIdx.x;  // 1024
    float v0 = 0.f, v1 = 0.f;
#pragma unroll
    for (int p = 0; p < 8; ++p) {
        v0 += lpart[p * BATCH + tid];
        v1 += lpart[p * BATCH + tid + 1024];
    }
    sm[tid] = fmaxf(v0, v1);
    __syncthreads();
    for (int off = 512; off; off >>= 1) {
        if (tid < off) sm[tid] = fmaxf(sm[tid], sm[tid + off]);
        __syncthreads();
    }
    const float M = sm[0];
    __syncthreads();
    const float e0 = expf(v0 - M), e1 = expf(v1 - M);
    sm[tid] = e0 + e1;
    __syncthreads();
    for (int off = 512; off; off >>= 1) {
        if (tid < off) sm[tid] += sm[tid + off];
        __syncthreads();
    }
    const float S = sm[0];
    Bw[tid] = e0 / S;
    Bw[tid + 1024] = e1 / S;
}

// ---------------------------------------------------------------------------
// C1: partial cvec[p][i] = sum_{b in chunk p} Bw[b] * Ht_t[b][i]
// ---------------------------------------------------------------------------
__global__ void ct_part_kernel(const float* __restrict__ Bw, const float* __restrict__ Ht_t,
                               float* __restrict__ ctpart) {
    const int i = threadIdx.x;        // 512
    const int p = blockIdx.x;         // 32
    const float* base = Ht_t + (size_t)p * 64 * HIDDEN;
    const float* bw = Bw + p * 64;
    float acc = 0.f;
#pragma unroll 8
    for (int b = 0; b < 64; ++b) acc += bw[b] * base[(size_t)b * HIDDEN + i];
    ctpart[(size_t)p * HIDDEN + i] = acc;
}

// ---------------------------------------------------------------------------
// C2: ct_row += sum_p ctpart;  yscal = ct_row . w[24:] + b00; (last step: y out)
// ---------------------------------------------------------------------------
__global__ void ct_reduce_kernel(const float* __restrict__ ctpart, float* __restrict__ ct_row,
                                 const float* __restrict__ w, const float* __restrict__ b00,
                                 float* __restrict__ yscal, const float* __restrict__ yr_dot,
                                 float* __restrict__ y_out) {
    __shared__ float sm[512];
    const int i = threadIdx.x;  // 512
    float acc = 0.f;
#pragma unroll
    for (int p = 0; p < 32; ++p) acc += ctpart[p * HIDDEN + i];
    const float c = ct_row[i] + acc;
    ct_row[i] = c;
    sm[i] = c * w[WINDOW + i];
    __syncthreads();
    for (int off = 256; off; off >>= 1) {
        if (i < off) sm[i] += sm[i + off];
        __syncthreads();
    }
    const float ys = sm[0] + b00[0];
    if (i == 0) yscal[0] = ys;
    if (y_out != nullptr) {
        for (int b = i; b < BATCH; b += 512) y_out[b] = yr_dot[b] + ys;
    }
}

// ---------------------------------------------------------------------------
// D: gates[b][j] = d0 @ Whh^T + y_fake[b]*Wih[j] + bih[j] + bhh[j]
// ---------------------------------------------------------------------------
__global__ __launch_bounds__(256) void gates_kernel(const float* __restrict__ d0,
                                                    const float* __restrict__ Whh,
                                                    const float* __restrict__ Wih,
                                                    const float* __restrict__ bih,
                                                    const float* __restrict__ bhh,
                                                    const float* __restrict__ yr_dot,
                                                    const float* __restrict__ yscal,
                                                    float* __restrict__ gates) {
    __shared__ float As[16][64];
    __shared__ float Bs[16][64];
    float acc[4][4] = {};
    const int tid = threadIdx.x;
    const int m0 = blockIdx.x * 64, n0 = blockIdx.y * 64;
    gemm_tile(d0, HIDDEN, Whh, HIDDEN, HIDDEN, acc, As, Bs, m0, n0, tid);
    const int ty = tid >> 4, tx = tid & 15;
    const float ys = yscal[0];
#pragma unroll
    for (int r = 0; r < 4; ++r) {
        const int b = m0 + (ty << 2) + r;
        const float yf = yr_dot[b] + ys;
        const int j0 = n0 + (tx << 2);
        float4 out;
        out.x = acc[r][0] + yf * Wih[j0 + 0] + bih[j0 + 0] + bhh[j0 + 0];
        out.y = acc[r][1] + yf * Wih[j0 + 1] + bih[j0 + 1] + bhh[j0 + 1];
        out.z = acc[r][2] + yf * Wih[j0 + 2] + bih[j0 + 2] + bhh[j0 + 2];
        out.w = acc[r][3] + yf * Wih[j0 + 3] + bih[j0 + 3] + bhh[j0 + 3];
        *(float4*)&gates[(size_t)b * H4 + j0] = out;
    }
}

// ---------------------------------------------------------------------------
// E: LSTM elementwise update (ping-pong state buffers)
// ---------------------------------------------------------------------------
__device__ __forceinline__ float sigmoidf(float x) { return 1.f / (1.f + expf(-x)); }

__global__ void lstm_update_kernel(const float* __restrict__ gates,
                                   const float* __restrict__ s_old,
                                   float* __restrict__ s_new, float* __restrict__ d_new) {
    const int idx = blockIdx.x * blockDim.x + threadIdx.x;  // BATCH*HIDDEN
    const int b = idx >> 9, i = idx & 511;
    const float* g = gates + (size_t)b * H4;
    const float ig = g[i], fg = g[512 + i], gg = g[1024 + i], og = g[1536 + i];
    const float sn = sigmoidf(fg) * s_old[idx] + sigmoidf(ig) * tanhf(gg);
    const float dn = sigmoidf(og) * tanhf(sn);
    s_new[idx] = sn;
    d_new[idx] = dn;
}

// ---------------------------------------------------------------------------
extern "C" void kernel_launch(void* const* d_in, const int* in_sizes, int n_in,
                              void* d_out, int out_size, void* d_ws, size_t ws_size,
                              hipStream_t stream) {
    const float* Z      = (const float*)d_in[0];
    const float* d_init = (const float*)d_in[1];
    const float* s_init = (const float*)d_in[2];
    const float* y_real = (const float*)d_in[3];
    const float* vd     = (const float*)d_in[4];
    const float* Wd     = (const float*)d_in[5];
    const float* Ud     = (const float*)d_in[6];
    const float* w      = (const float*)d_in[7];
    const float* b00    = (const float*)d_in[8];
    const float* conv_w = (const float*)d_in[9];
    const float* conv_b = (const float*)d_in[10];
    const float* Wih    = (const float*)d_in[11];
    const float* Whh    = (const float*)d_in[12];
    const float* bih    = (const float*)d_in[13];
    const float* bhh    = (const float*)d_in[14];

    float* ws = (float*)d_ws;
    size_t off = 0;
    float* Ht = ws + off;      off += (size_t)WINDOW * BATCH * HIDDEN;  // 25.2M
    float* G  = ws + off;      off += (size_t)WINDOW * BATCH * HIDDEN;  // 25.2M
    float* dbuf[2];
    dbuf[0] = ws + off;        off += (size_t)BATCH * HIDDEN;
    dbuf[1] = ws + off;        off += (size_t)BATCH * HIDDEN;
    float* sbuf[2];
    sbuf[0] = ws + off;        off += (size_t)BATCH * HIDDEN;
    sbuf[1] = ws + off;        off += (size_t)BATCH * HIDDEN;
    float* gates  = ws + off;  off += (size_t)BATCH * H4;               // 4.2M
    float* lpart  = ws + off;  off += (size_t)8 * BATCH;
    float* Bw     = ws + off;  off += BATCH;
    float* yr_dot = ws + off;  off += BATCH;
    float* ctpart = ws + off;  off += (size_t)32 * HIDDEN;
    float* ct_row = ws + off;  off += HIDDEN;
    float* yscal  = ws + off;  off += 1;

    float* out = (float*)d_out;
    float* y_out = out;                               // [2048]
    float* d_out_f = out + BATCH;                     // [2048*512]
    float* s_out_f = out + BATCH + (size_t)BATCH * HIDDEN;

    const size_t state_bytes = (size_t)BATCH * HIDDEN * sizeof(float);

    // --- precompute ---
    conv_kernel<<<BATCH, 256, 0, stream>>>(Z, conv_w, conv_b, Ht);
    {
        dim3 grid((WINDOW * BATCH) / 64, HIDDEN / 64);
        g_gemm_kernel<<<grid, 256, 0, stream>>>(Ht, Ud, G);
    }
    init_kernel<<<8, 256, 0, stream>>>(y_real, w, yr_dot, ct_row);
    hipMemcpyAsync(dbuf[0], d_init, state_bytes, hipMemcpyDeviceToDevice, stream);
    hipMemcpyAsync(sbuf[0], s_init, state_bytes, hipMemcpyDeviceToDevice, stream);

    // --- scan over 24 steps ---
    int cur = 0;
    for (int t = 0; t < WINDOW; ++t) {
        const float* Gt   = G  + (size_t)t * BATCH * HIDDEN;
        const float* Ht_t = Ht + (size_t)t * BATCH * HIDDEN;
        const float* d_cur = dbuf[cur];
        const float* s_cur = sbuf[cur];
        float* d_nxt = dbuf[1 - cur];
        float* s_nxt = sbuf[1 - cur];

        {
            dim3 grid(BATCH / 64, HIDDEN / 64);  // 32 x 8
            s1_kernel<<<grid, 256, 0, stream>>>(d_cur, s_cur, Wd, Gt, vd, lpart);
        }
        softmax_kernel<<<1, 1024, 0, stream>>>(lpart, Bw);
        ct_part_kernel<<<32, 512, 0, stream>>>(Bw, Ht_t, ctpart);
        ct_reduce_kernel<<<1, 512, 0, stream>>>(ctpart, ct_row, w, b00, yscal, yr_dot,
                                                (t == WINDOW - 1) ? y_out : nullptr);
        {
            dim3 grid(BATCH / 64, H4 / 64);  // 32 x 32
            gates_kernel<<<grid, 256, 0, stream>>>(d_cur, Whh, Wih, bih, bhh, yr_dot,
                                                   yscal, gates);
        }
        lstm_update_kernel<<<(BATCH * HIDDEN) / 256, 256, 0, stream>>>(gates, s_cur,
                                                                       s_nxt, d_nxt);
        cur = 1 - cur;
    }

    // --- final state out ---
    hipMemcpyAsync(d_out_f, dbuf[cur], state_bytes, hipMemcpyDeviceToDevice, stream);
    hipMemcpyAsync(s_out_f, sbuf[cur], state_bytes, hipMemcpyDeviceToDevice, stream);
}

// Round 2
// 1519.710 us; speedup vs baseline: 2.5968x; 2.5968x over previous
//
#include <hip/hip_runtime.h>
#include <math.h>

#define HIDDEN 512
#define WINDOW 24
#define KSZ 3
#define BATCH 2048
#define L_IN (HIDDEN + KSZ - 1)   // 514
#define H4 (4 * HIDDEN)           // 2048
#define LDT 40                    // padded LDS row stride (shorts) for 32-k tiles

typedef short short8 __attribute__((ext_vector_type(8)));
typedef float floatx4 __attribute__((ext_vector_type(4)));

__device__ __forceinline__ floatx4 mfma16(short8 a, short8 b, floatx4 c) {
    return __builtin_amdgcn_mfma_f32_16x16x32_bf16(a, b, c, 0, 0, 0);
}

__device__ __forceinline__ unsigned short f2bf(float x) {
    union { float f; unsigned u; } v; v.f = x;
    unsigned r = v.u + 0x7fff + ((v.u >> 16) & 1);   // RTNE
    return (unsigned short)(r >> 16);
}
__device__ __forceinline__ float bf2f(unsigned short u) {
    union { unsigned u; float f; } v; v.u = ((unsigned)u) << 16;
    return v.f;
}
__device__ __forceinline__ float sigmoidf(float x) { return 1.f / (1.f + expf(-x)); }

// stage a 64x32 bf16 tile (row-major, leading dim ld in elems) into LDS rows of LDT
__device__ __forceinline__ void stage64x32(const unsigned short* __restrict__ src, int ld,
                                           short* dst, int tid) {
    const int row = tid >> 2, seg = tid & 3;
    float4 v = *(const float4*)(src + (size_t)row * ld + seg * 8);
    *(float4*)(dst + row * LDT + seg * 8) = v;
}

// ---------------------------------------------------------------------------
// cvt: fp32 -> bf16
// ---------------------------------------------------------------------------
__global__ void cvt_kernel(const float* __restrict__ src, unsigned short* __restrict__ dst,
                           int n) {
    const int i = blockIdx.x * blockDim.x + threadIdx.x;
    if (i < n) dst[i] = f2bf(src[i]);
}

// ---------------------------------------------------------------------------
// conv1d(2->24, k=3, valid) + bias + relu -> Htb bf16 [t][b][i]
// ---------------------------------------------------------------------------
__global__ void conv_kernel(const float* __restrict__ Z, const float* __restrict__ conv_w,
                            const float* __restrict__ conv_b,
                            unsigned short* __restrict__ Htb) {
    __shared__ float cw[WINDOW * 2 * KSZ];
    __shared__ float cb[WINDOW];
    const int b = blockIdx.x;
    if (threadIdx.x < WINDOW * 2 * KSZ) cw[threadIdx.x] = conv_w[threadIdx.x];
    if (threadIdx.x < WINDOW) cb[threadIdx.x] = conv_b[threadIdx.x];
    __syncthreads();
    const float* z0 = Z + (size_t)b * L_IN;
    const float* z1 = Z + (size_t)BATCH * L_IN + (size_t)b * L_IN;
    for (int i = threadIdx.x; i < HIDDEN; i += blockDim.x) {
        const float a0 = z0[i], a1 = z0[i + 1], a2 = z0[i + 2];
        const float b0 = z1[i], b1 = z1[i + 1], b2 = z1[i + 2];
#pragma unroll
        for (int o = 0; o < WINDOW; ++o) {
            const float* wc = cw + o * 6;
            float v = cb[o] + a0 * wc[0] + a1 * wc[1] + a2 * wc[2]
                            + b0 * wc[3] + b1 * wc[4] + b2 * wc[5];
            Htb[((size_t)o * BATCH + b) * HIDDEN + i] = f2bf(fmaxf(v, 0.f));
        }
    }
}

// ---------------------------------------------------------------------------
// G = Htb[49152 x 512] @ Udb^T  (fp32 out).  64x64 tile, 4 waves, MFMA.
// ---------------------------------------------------------------------------
__global__ __launch_bounds__(256) void g_gemm_mfma(const unsigned short* __restrict__ Htb,
                                                   const unsigned short* __restrict__ Udb,
                                                   float* __restrict__ G) {
    __shared__ __align__(16) short As[64 * LDT];
    __shared__ __align__(16) short Bs[64 * LDT];
    const int tid = threadIdx.x;
    const int wave = tid >> 6, lane = tid & 63;
    const int wm = wave >> 1, wn = wave & 1;
    const int quad = lane >> 4, lr = lane & 15, qk = quad * 8;
    const int m0 = blockIdx.x * 64, n0 = blockIdx.y * 64;
    floatx4 acc[2][2] = {};
    for (int k0 = 0; k0 < HIDDEN; k0 += 32) {
        stage64x32(Htb + (size_t)m0 * HIDDEN + k0, HIDDEN, As, tid);
        stage64x32(Udb + (size_t)n0 * HIDDEN + k0, HIDDEN, Bs, tid);
        __syncthreads();
        short8 a0 = *(const short8*)(As + (wm * 32 + lr) * LDT + qk);
        short8 a1 = *(const short8*)(As + (wm * 32 + 16 + lr) * LDT + qk);
        short8 b0 = *(const short8*)(Bs + (wn * 32 + lr) * LDT + qk);
        short8 b1 = *(const short8*)(Bs + (wn * 32 + 16 + lr) * LDT + qk);
        acc[0][0] = mfma16(a0, b0, acc[0][0]);
        acc[0][1] = mfma16(a0, b1, acc[0][1]);
        acc[1][0] = mfma16(a1, b0, acc[1][0]);
        acc[1][1] = mfma16(a1, b1, acc[1][1]);
        __syncthreads();
    }
#pragma unroll
    for (int mf = 0; mf < 2; ++mf)
#pragma unroll
        for (int nf = 0; nf < 2; ++nf)
#pragma unroll
            for (int r = 0; r < 4; ++r) {
                const int m = m0 + wm * 32 + mf * 16 + quad * 4 + r;
                const int n = n0 + wn * 32 + nf * 16 + lr;
                G[(size_t)m * HIDDEN + n] = acc[mf][nf][r];
            }
}

// ---------------------------------------------------------------------------
// init: yr_dot[b] = y_real[b,:24] . w[:24];  ct_row = 0
// ---------------------------------------------------------------------------
__global__ void init_kernel(const float* __restrict__ y_real, const float* __restrict__ w,
                            float* __restrict__ yr_dot, float* __restrict__ ct_row) {
    const int tid = blockIdx.x * blockDim.x + threadIdx.x;
    if (tid < BATCH) {
        float s = 0.f;
#pragma unroll
        for (int j = 0; j < WINDOW; ++j) s += y_real[tid * WINDOW + j] * w[j];
        yr_dot[tid] = s;
    }
    if (tid < HIDDEN) ct_row[tid] = 0.f;
}

// ---------------------------------------------------------------------------
// S1: lpart[by][b] = sum_i tanh(d0@WdA^T + s0@WdB^T + G_t)[b,i] * vd[i]
// 64x64 tile MFMA, two K=512 passes (d0 | s0 halves of Wd's K dim).
// ---------------------------------------------------------------------------
__global__ __launch_bounds__(256) void s1_mfma(const unsigned short* __restrict__ db,
                                               const unsigned short* __restrict__ sb,
                                               const unsigned short* __restrict__ Wdb,
                                               const float* __restrict__ Gt,
                                               const float* __restrict__ vd,
                                               float* __restrict__ lpart) {
    __shared__ __align__(16) short As[64 * LDT];
    __shared__ __align__(16) short Bs[64 * LDT];
    __shared__ float red[2][64];
    const int tid = threadIdx.x;
    const int wave = tid >> 6, lane = tid & 63;
    const int wm = wave >> 1, wn = wave & 1;
    const int quad = lane >> 4, lr = lane & 15, qk = quad * 8;
    const int m0 = blockIdx.x * 64, n0 = blockIdx.y * 64;
    floatx4 acc[2][2] = {};
#pragma unroll
    for (int pass = 0; pass < 2; ++pass) {
        const unsigned short* A = pass ? sb : db;
        const unsigned short* B = Wdb + pass * HIDDEN;  // k-offset into [512][1024]
        for (int k0 = 0; k0 < HIDDEN; k0 += 32) {
            stage64x32(A + (size_t)m0 * HIDDEN + k0, HIDDEN, As, tid);
            stage64x32(B + (size_t)n0 * (2 * HIDDEN) + k0, 2 * HIDDEN, Bs, tid);
            __syncthreads();
            short8 a0 = *(const short8*)(As + (wm * 32 + lr) * LDT + qk);
            short8 a1 = *(const short8*)(As + (wm * 32 + 16 + lr) * LDT + qk);
            short8 b0 = *(const short8*)(Bs + (wn * 32 + lr) * LDT + qk);
            short8 b1 = *(const short8*)(Bs + (wn * 32 + 16 + lr) * LDT + qk);
            acc[0][0] = mfma16(a0, b0, acc[0][0]);
            acc[0][1] = mfma16(a0, b1, acc[0][1]);
            acc[1][0] = mfma16(a1, b0, acc[1][0]);
            acc[1][1] = mfma16(a1, b1, acc[1][1]);
            __syncthreads();
        }
    }
    // epilogue: tanh(acc + Gt)*vd, reduce over columns
#pragma unroll
    for (int mf = 0; mf < 2; ++mf) {
        float rs[4];
#pragma unroll
        for (int r = 0; r < 4; ++r) {
            const int b = m0 + wm * 32 + mf * 16 + quad * 4 + r;
            float v = 0.f;
#pragma unroll
            for (int nf = 0; nf < 2; ++nf) {
                const int i = n0 + wn * 32 + nf * 16 + lr;
                v += tanhf(acc[mf][nf][r] + Gt[(size_t)b * HIDDEN + i]) * vd[i];
            }
            for (int msk = 1; msk < 16; msk <<= 1) v += __shfl_xor(v, msk, 16);
            rs[r] = v;
        }
        if (lr == 0)
#pragma unroll
            for (int r = 0; r < 4; ++r)
                red[wn][wm * 32 + mf * 16 + quad * 4 + r] = rs[r];
    }
    __syncthreads();
    if (tid < 64)
        lpart[(size_t)blockIdx.y * BATCH + m0 + tid] = red[0][tid] + red[1][tid];
}

// ---------------------------------------------------------------------------
// softmax over batch (2048), summing 8 column-block partials first
// ---------------------------------------------------------------------------
__global__ void softmax_kernel(const float* __restrict__ lpart, float* __restrict__ Bw) {
    __shared__ float sm[1024];
    const int tid = threadIdx.x;  // 1024
    float v0 = 0.f, v1 = 0.f;
#pragma unroll
    for (int p = 0; p < 8; ++p) {
        v0 += lpart[p * BATCH + tid];
        v1 += lpart[p * BATCH + tid + 1024];
    }
    sm[tid] = fmaxf(v0, v1);
    __syncthreads();
    for (int off = 512; off; off >>= 1) {
        if (tid < off) sm[tid] = fmaxf(sm[tid], sm[tid + off]);
        __syncthreads();
    }
    const float M = sm[0];
    __syncthreads();
    const float e0 = expf(v0 - M), e1 = expf(v1 - M);
    sm[tid] = e0 + e1;
    __syncthreads();
    for (int off = 512; off; off >>= 1) {
        if (tid < off) sm[tid] += sm[tid + off];
        __syncthreads();
    }
    const float S = sm[0];
    Bw[tid] = e0 / S;
    Bw[tid + 1024] = e1 / S;
}

// ---------------------------------------------------------------------------
// C1: ctpart[p][i] = sum_{b in chunk p} Bw[b] * Ht_t[b][i]   (bf16 H)
// ---------------------------------------------------------------------------
__global__ void ct_part_kernel(const float* __restrict__ Bw,
                               const unsigned short* __restrict__ Htb_t,
                               float* __restrict__ ctpart) {
    const int i = threadIdx.x;        // 512
    const int p = blockIdx.x;         // 32
    const unsigned short* base = Htb_t + (size_t)p * 64 * HIDDEN;
    const float* bw = Bw + p * 64;
    float acc = 0.f;
#pragma unroll 8
    for (int b = 0; b < 64; ++b) acc += bw[b] * bf2f(base[(size_t)b * HIDDEN + i]);
    ctpart[(size_t)p * HIDDEN + i] = acc;
}

// ---------------------------------------------------------------------------
// C2: ct_row += sum_p ctpart;  yscal = ct_row . w[24:] + b00; (last step: y out)
// ---------------------------------------------------------------------------
__global__ void ct_reduce_kernel(const float* __restrict__ ctpart, float* __restrict__ ct_row,
                                 const float* __restrict__ w, const float* __restrict__ b00,
                                 float* __restrict__ yscal, const float* __restrict__ yr_dot,
                                 float* __restrict__ y_out) {
    __shared__ float sm[512];
    const int i = threadIdx.x;  // 512
    float acc = 0.f;
#pragma unroll
    for (int p = 0; p < 32; ++p) acc += ctpart[p * HIDDEN + i];
    const float c = ct_row[i] + acc;
    ct_row[i] = c;
    sm[i] = c * w[WINDOW + i];
    __syncthreads();
    for (int off = 256; off; off >>= 1) {
        if (i < off) sm[i] += sm[i + off];
        __syncthreads();
    }
    const float ys = sm[0] + b00[0];
    if (i == 0) yscal[0] = ys;
    if (y_out != nullptr) {
        for (int b = i; b < BATCH; b += 512) y_out[b] = yr_dot[b] + ys;
    }
}

// ---------------------------------------------------------------------------
// gates GEMM (4 gates as separate 512x512 B-matrices) + fused LSTM update.
// Tile 64(batch) x 64(hidden), 4 waves, per-gate accumulators.
// ---------------------------------------------------------------------------
__global__ __launch_bounds__(256) void gates_lstm_mfma(
        const unsigned short* __restrict__ db, const unsigned short* __restrict__ Whhb,
        const float* __restrict__ Wih, const float* __restrict__ bih,
        const float* __restrict__ bhh, const float* __restrict__ yr_dot,
        const float* __restrict__ yscal, const float* __restrict__ s_old,
        float* __restrict__ s_new, float* __restrict__ d_new,
        unsigned short* __restrict__ sb_new, unsigned short* __restrict__ db_new) {
    __shared__ __align__(16) short As[64 * LDT];
    __shared__ __align__(16) short Bs[4][64 * LDT];
    const int tid = threadIdx.x;
    const int wave = tid >> 6, lane = tid & 63;
    const int wm = wave >> 1, wn = wave & 1;
    const int quad = lane >> 4, lr = lane & 15, qk = quad * 8;
    const int m0 = blockIdx.x * 64, n0 = blockIdx.y * 64;
    floatx4 acc[4][2][2] = {};
    for (int k0 = 0; k0 < HIDDEN; k0 += 32) {
        stage64x32(db + (size_t)m0 * HIDDEN + k0, HIDDEN, As, tid);
#pragma unroll
        for (int g = 0; g < 4; ++g)
            stage64x32(Whhb + (size_t)(g * HIDDEN + n0) * HIDDEN + k0, HIDDEN, Bs[g], tid);
        __syncthreads();
        short8 a0 = *(const short8*)(As + (wm * 32 + lr) * LDT + qk);
        short8 a1 = *(const short8*)(As + (wm * 32 + 16 + lr) * LDT + qk);
#pragma unroll
        for (int g = 0; g < 4; ++g) {
            short8 b0 = *(const short8*)(Bs[g] + (wn * 32 + lr) * LDT + qk);
            short8 b1 = *(const short8*)(Bs[g] + (wn * 32 + 16 + lr) * LDT + qk);
            acc[g][0][0] = mfma16(a0, b0, acc[g][0][0]);
            acc[g][0][1] = mfma16(a0, b1, acc[g][0][1]);
            acc[g][1][0] = mfma16(a1, b0, acc[g][1][0]);
            acc[g][1][1] = mfma16(a1, b1, acc[g][1][1]);
        }
        __syncthreads();
    }
    const float ys = yscal[0];
#pragma unroll
    for (int nf = 0; nf < 2; ++nf) {
        const int i = n0 + wn * 32 + nf * 16 + lr;
        float wi[4], cb[4];
#pragma unroll
        for (int g = 0; g < 4; ++g) {
            wi[g] = Wih[g * HIDDEN + i];
            cb[g] = bih[g * HIDDEN + i] + bhh[g * HIDDEN + i];
        }
#pragma unroll
        for (int mf = 0; mf < 2; ++mf) {
#pragma unroll
            for (int r = 0; r < 4; ++r) {
                const int b = m0 + wm * 32 + mf * 16 + quad * 4 + r;
                const float yf = yr_dot[b] + ys;
                const size_t idx = (size_t)b * HIDDEN + i;
                const float ig = acc[0][mf][nf][r] + yf * wi[0] + cb[0];
                const float fg = acc[1][mf][nf][r] + yf * wi[1] + cb[1];
                const float gg = acc[2][mf][nf][r] + yf * wi[2] + cb[2];
                const float og = acc[3][mf][nf][r] + yf * wi[3] + cb[3];
                const float sn = sigmoidf(fg) * s_old[idx] + sigmoidf(ig) * tanhf(gg);
                const float dn = sigmoidf(og) * tanhf(sn);
                s_new[idx] = sn;
                d_new[idx] = dn;
                sb_new[idx] = f2bf(sn);
                db_new[idx] = f2bf(dn);
            }
        }
    }
}

// ---------------------------------------------------------------------------
extern "C" void kernel_launch(void* const* d_in, const int* in_sizes, int n_in,
                              void* d_out, int out_size, void* d_ws, size_t ws_size,
                              hipStream_t stream) {
    const float* Z      = (const float*)d_in[0];
    const float* d_init = (const float*)d_in[1];
    const float* s_init = (const float*)d_in[2];
    const float* y_real = (const float*)d_in[3];
    const float* vd     = (const float*)d_in[4];
    const float* Wd     = (const float*)d_in[5];
    const float* Ud     = (const float*)d_in[6];
    const float* w      = (const float*)d_in[7];
    const float* b00    = (const float*)d_in[8];
    const float* conv_w = (const float*)d_in[9];
    const float* conv_b = (const float*)d_in[10];
    const float* Wih    = (const float*)d_in[11];
    const float* bih    = (const float*)d_in[13 - 2];  // d_in[11] is Wih, keep order below
    const float* Whh    = (const float*)d_in[12];
    const float* bih_   = (const float*)d_in[13];
    const float* bhh    = (const float*)d_in[14];
    (void)bih;

    float* ws = (float*)d_ws;
    size_t off = 0;
    unsigned short* Htb = (unsigned short*)(ws + off);  off += (size_t)WINDOW * BATCH * HIDDEN / 2;
    float* G  = ws + off;                                off += (size_t)WINDOW * BATCH * HIDDEN;
    float* dbuf[2];
    dbuf[0] = ws + off;  off += (size_t)BATCH * HIDDEN;
    dbuf[1] = ws + off;  off += (size_t)BATCH * HIDDEN;
    float* sbuf[2];
    sbuf[0] = ws + off;  off += (size_t)BATCH * HIDDEN;
    sbuf[1] = ws + off;  off += (size_t)BATCH * HIDDEN;
    unsigned short* dbb[2];
    dbb[0] = (unsigned short*)(ws + off);  off += (size_t)BATCH * HIDDEN / 2;
    dbb[1] = (unsigned short*)(ws + off);  off += (size_t)BATCH * HIDDEN / 2;
    unsigned short* sbb[2];
    sbb[0] = (unsigned short*)(ws + off);  off += (size_t)BATCH * HIDDEN / 2;
    sbb[1] = (unsigned short*)(ws + off);  off += (size_t)BATCH * HIDDEN / 2;
    unsigned short* Wdb  = (unsigned short*)(ws + off);  off += (size_t)HIDDEN * 2 * HIDDEN / 2;
    unsigned short* Udb  = (unsigned short*)(ws + off);  off += (size_t)HIDDEN * HIDDEN / 2;
    unsigned short* Whhb = (unsigned short*)(ws + off);  off += (size_t)H4 * HIDDEN / 2;
    float* lpart  = ws + off;  off += (size_t)8 * BATCH;
    float* Bw     = ws + off;  off += BATCH;
    float* yr_dot = ws + off;  off += BATCH;
    float* ctpart = ws + off;  off += (size_t)32 * HIDDEN;
    float* ct_row = ws + off;  off += HIDDEN;
    float* yscal  = ws + off;  off += 1;

    float* out = (float*)d_out;
    float* y_out   = out;
    float* d_out_f = out + BATCH;
    float* s_out_f = out + BATCH + (size_t)BATCH * HIDDEN;

    const size_t state_bytes = (size_t)BATCH * HIDDEN * sizeof(float);

    // --- dtype conversions (once per call) ---
    cvt_kernel<<<(HIDDEN * 2 * HIDDEN + 255) / 256, 256, 0, stream>>>(Wd, Wdb, HIDDEN * 2 * HIDDEN);
    cvt_kernel<<<(HIDDEN * HIDDEN + 255) / 256, 256, 0, stream>>>(Ud, Udb, HIDDEN * HIDDEN);
    cvt_kernel<<<(H4 * HIDDEN + 255) / 256, 256, 0, stream>>>(Whh, Whhb, H4 * HIDDEN);
    cvt_kernel<<<(BATCH * HIDDEN + 255) / 256, 256, 0, stream>>>(d_init, dbb[0], BATCH * HIDDEN);
    cvt_kernel<<<(BATCH * HIDDEN + 255) / 256, 256, 0, stream>>>(s_init, sbb[0], BATCH * HIDDEN);

    // --- precompute ---
    conv_kernel<<<BATCH, 256, 0, stream>>>(Z, conv_w, conv_b, Htb);
    {
        dim3 grid((WINDOW * BATCH) / 64, HIDDEN / 64);  // 768 x 8
        g_gemm_mfma<<<grid, 256, 0, stream>>>(Htb, Udb, G);
    }
    init_kernel<<<8, 256, 0, stream>>>(y_real, w, yr_dot, ct_row);
    hipMemcpyAsync(dbuf[0], d_init, state_bytes, hipMemcpyDeviceToDevice, stream);
    hipMemcpyAsync(sbuf[0], s_init, state_bytes, hipMemcpyDeviceToDevice, stream);

    // --- scan over 24 steps ---
    int cur = 0;
    for (int t = 0; t < WINDOW; ++t) {
        const float* Gt = G + (size_t)t * BATCH * HIDDEN;
        const unsigned short* Htb_t = Htb + (size_t)t * BATCH * HIDDEN;

        {
            dim3 grid(BATCH / 64, HIDDEN / 64);  // 32 x 8
            s1_mfma<<<grid, 256, 0, stream>>>(dbb[cur], sbb[cur], Wdb, Gt, vd, lpart);
        }
        softmax_kernel<<<1, 1024, 0, stream>>>(lpart, Bw);
        ct_part_kernel<<<32, 512, 0, stream>>>(Bw, Htb_t, ctpart);
        ct_reduce_kernel<<<1, 512, 0, stream>>>(ctpart, ct_row, w, b00, yscal, yr_dot,
                                                (t == WINDOW - 1) ? y_out : nullptr);
        {
            dim3 grid(BATCH / 64, HIDDEN / 64);  // 32 x 8
            gates_lstm_mfma<<<grid, 256, 0, stream>>>(dbb[cur], Whhb, Wih, bih_, bhh,
                                                      yr_dot, yscal, sbuf[cur],
                                                      sbuf[1 - cur], dbuf[1 - cur],
                                                      sbb[1 - cur], dbb[1 - cur]);
        }
        cur = 1 - cur;
    }

    // --- final state out ---
    hipMemcpyAsync(d_out_f, dbuf[cur], state_bytes, hipMemcpyDeviceToDevice, stream);
    hipMemcpyAsync(s_out_f, sbuf[cur], state_bytes, hipMemcpyDeviceToDevice, stream);
}

// Round 4
// 1265.402 us; speedup vs baseline: 3.1187x; 1.2010x over previous
//
#include <hip/hip_runtime.h>
#include <math.h>

#define HIDDEN 512
#define WINDOW 24
#define KSZ 3
#define BATCH 2048
#define L_IN 514
#define H4 2048
#define LDT 40                    // padded LDS row stride (shorts) for 32-k tiles
#define BH (BATCH * HIDDEN)

typedef short short8 __attribute__((ext_vector_type(8)));
typedef float floatx4 __attribute__((ext_vector_type(4)));

__device__ __forceinline__ floatx4 mfma16(short8 a, short8 b, floatx4 c) {
    return __builtin_amdgcn_mfma_f32_16x16x32_bf16(a, b, c, 0, 0, 0);
}
__device__ __forceinline__ unsigned short f2bf(float x) {
    union { float f; unsigned u; } v; v.f = x;
    unsigned r = v.u + 0x7fff + ((v.u >> 16) & 1);   // RTNE
    return (unsigned short)(r >> 16);
}
__device__ __forceinline__ float bf2f(unsigned short u) {
    union { unsigned u; float f; } v; v.u = ((unsigned)u) << 16;
    return v.f;
}
__device__ __forceinline__ float sigmoidf(float x) { return 1.f / (1.f + expf(-x)); }

// ---------------------------------------------------------------------------
// cvt5: fp32 -> bf16 for Wd, Ud, Whh, d_init, s_init (one kernel, float4-wide)
// ---------------------------------------------------------------------------
__global__ void cvt5_kernel(const float* __restrict__ s0, unsigned short* __restrict__ d0,
                            const float* __restrict__ s1, unsigned short* __restrict__ d1,
                            const float* __restrict__ s2, unsigned short* __restrict__ d2,
                            const float* __restrict__ s3, unsigned short* __restrict__ d3,
                            const float* __restrict__ s4, unsigned short* __restrict__ d4) {
    const int g = blockIdx.x * blockDim.x + threadIdx.x;   // one float4 per thread
    const float* src; unsigned short* dst; int off;
    if      (g < 131072) { src = s0; dst = d0; off = g; }
    else if (g < 196608) { src = s1; dst = d1; off = g - 131072; }
    else if (g < 458752) { src = s2; dst = d2; off = g - 196608; }
    else if (g < 720896) { src = s3; dst = d3; off = g - 458752; }
    else if (g < 983040) { src = s4; dst = d4; off = g - 720896; }
    else return;
    float4 v = ((const float4*)src)[off];
    uint2 u;
    u.x = (unsigned)f2bf(v.x) | ((unsigned)f2bf(v.y) << 16);
    u.y = (unsigned)f2bf(v.z) | ((unsigned)f2bf(v.w) << 16);
    ((uint2*)dst)[off] = u;
}

// ---------------------------------------------------------------------------
// conv1d(2->24, k=3, valid) + bias + relu -> Htb bf16 [t][b][i], 2-packed stores
// ---------------------------------------------------------------------------
__global__ void conv_kernel(const float* __restrict__ Z, const float* __restrict__ conv_w,
                            const float* __restrict__ conv_b,
                            unsigned int* __restrict__ Htu) {
    __shared__ float cw[WINDOW * 6];
    __shared__ float cb[WINDOW];
    const int b = blockIdx.x;
    if (threadIdx.x < WINDOW * 6) cw[threadIdx.x] = conv_w[threadIdx.x];
    if (threadIdx.x < WINDOW) cb[threadIdx.x] = conv_b[threadIdx.x];
    __syncthreads();
    const float* z0 = Z + (size_t)b * L_IN;
    const float* z1 = z0 + (size_t)BATCH * L_IN;
    const int i0 = threadIdx.x * 2;
    const float a0 = z0[i0], a1 = z0[i0 + 1], a2 = z0[i0 + 2], a3 = z0[i0 + 3];
    const float c0 = z1[i0], c1 = z1[i0 + 1], c2 = z1[i0 + 2], c3 = z1[i0 + 3];
#pragma unroll
    for (int o = 0; o < WINDOW; ++o) {
        const float* wc = cw + o * 6;
        float v0 = fmaxf(cb[o] + a0 * wc[0] + a1 * wc[1] + a2 * wc[2]
                               + c0 * wc[3] + c1 * wc[4] + c2 * wc[5], 0.f);
        float v1 = fmaxf(cb[o] + a1 * wc[0] + a2 * wc[1] + a3 * wc[2]
                               + c1 * wc[3] + c2 * wc[4] + c3 * wc[5], 0.f);
        Htu[((size_t)o * BATCH + b) * 256 + threadIdx.x] =
            (unsigned)f2bf(v0) | ((unsigned)f2bf(v1) << 16);
    }
}

// ---------------------------------------------------------------------------
// hw[t][b] = H_t[b,:] . w[24:]   (makes the ct vector unnecessary)
// ---------------------------------------------------------------------------
__global__ void hw_kernel(const unsigned short* __restrict__ Htb,
                          const float* __restrict__ w, float* __restrict__ hw) {
    const int row = blockIdx.x * 4 + (threadIdx.x >> 6);   // 0 .. 24*2048-1
    const int lane = threadIdx.x & 63;
    short8 v = *(const short8*)(Htb + (size_t)row * HIDDEN + lane * 8);
    float acc = 0.f;
#pragma unroll
    for (int j = 0; j < 8; ++j)
        acc += bf2f((unsigned short)v[j]) * w[WINDOW + lane * 8 + j];
    for (int m = 32; m; m >>= 1) acc += __shfl_xor(acc, m, 64);
    if (lane == 0) hw[row] = acc;
}

// ---------------------------------------------------------------------------
// Gb = Htb[49152 x 512] @ Udb^T  (bf16 out).  64x64 tile, 4 waves, MFMA.
// ---------------------------------------------------------------------------
__global__ __launch_bounds__(256) void g_gemm_mfma(const unsigned short* __restrict__ Htb,
                                                   const unsigned short* __restrict__ Udb,
                                                   unsigned short* __restrict__ Gb) {
    __shared__ __align__(16) short As[64 * LDT];
    __shared__ __align__(16) short Bs[64 * LDT];
    const int tid = threadIdx.x;
    const int wave = tid >> 6, lane = tid & 63;
    const int wm = wave >> 1, wn = wave & 1;
    const int quad = lane >> 4, lr = lane & 15, qk = quad * 8;
    const int m0 = blockIdx.x * 64, n0 = blockIdx.y * 64;
    const int arow = tid >> 2, aseg = tid & 3;
    floatx4 acc[2][2] = {};
    for (int k0 = 0; k0 < HIDDEN; k0 += 32) {
        *(float4*)(As + arow * LDT + aseg * 8) =
            *(const float4*)(Htb + (size_t)(m0 + arow) * HIDDEN + k0 + aseg * 8);
        *(float4*)(Bs + arow * LDT + aseg * 8) =
            *(const float4*)(Udb + (size_t)(n0 + arow) * HIDDEN + k0 + aseg * 8);
        __syncthreads();
        short8 a0 = *(const short8*)(As + (wm * 32 + lr) * LDT + qk);
        short8 a1 = *(const short8*)(As + (wm * 32 + 16 + lr) * LDT + qk);
        short8 b0 = *(const short8*)(Bs + (wn * 32 + lr) * LDT + qk);
        short8 b1 = *(const short8*)(Bs + (wn * 32 + 16 + lr) * LDT + qk);
        acc[0][0] = mfma16(a0, b0, acc[0][0]);
        acc[0][1] = mfma16(a0, b1, acc[0][1]);
        acc[1][0] = mfma16(a1, b0, acc[1][0]);
        acc[1][1] = mfma16(a1, b1, acc[1][1]);
        __syncthreads();
    }
#pragma unroll
    for (int mf = 0; mf < 2; ++mf)
#pragma unroll
        for (int nf = 0; nf < 2; ++nf)
#pragma unroll
            for (int r = 0; r < 4; ++r) {
                const int m = m0 + wm * 32 + mf * 16 + quad * 4 + r;
                const int n = n0 + wn * 32 + nf * 16 + lr;
                Gb[(size_t)m * HIDDEN + n] = f2bf(acc[mf][nf][r]);
            }
}

// ---------------------------------------------------------------------------
// init: yr_dot[b] = y_real[b,:24] . w[:24];  ctw = 0
// ---------------------------------------------------------------------------
__global__ void init_kernel(const float* __restrict__ y_real, const float* __restrict__ w,
                            float* __restrict__ yr_dot, float* __restrict__ ctw) {
    const int tid = blockIdx.x * blockDim.x + threadIdx.x;
    if (tid < BATCH) {
        float s = 0.f;
#pragma unroll
        for (int j = 0; j < WINDOW; ++j) s += y_real[tid * WINDOW + j] * w[j];
        yr_dot[tid] = s;
    }
    if (tid == 0) ctw[0] = 0.f;
}

// ---------------------------------------------------------------------------
// S1: lpart[nb][b] = sum_{i in nb-slice} tanh(d@WdA^T + s@WdB^T + G_t)*vd
// 64x32 tile, 512 blocks (2/CU), 4 waves: wm = row-half, wn = col-half(16).
// ---------------------------------------------------------------------------
__global__ __launch_bounds__(256) void s1_mfma(const unsigned short* __restrict__ db,
                                               const unsigned short* __restrict__ sb,
                                               const unsigned short* __restrict__ Wdb,
                                               const unsigned short* __restrict__ Gtb,
                                               const float* __restrict__ vd,
                                               float* __restrict__ lpart) {
    __shared__ __align__(16) short As[64 * LDT];
    __shared__ __align__(16) short Bs[32 * LDT];
    __shared__ float red[2][64];
    const int tid = threadIdx.x;
    const int wave = tid >> 6, lane = tid & 63;
    const int wm = wave >> 1, wn = wave & 1;
    const int quad = lane >> 4, lr = lane & 15, qk = quad * 8;
    const int m0 = (blockIdx.x & 31) * 64;
    const int nb = blockIdx.x >> 5;          // 0..15
    const int n0 = nb * 32;
    const int arow = tid >> 2, aseg = tid & 3;
    floatx4 acc[2] = {};
#pragma unroll
    for (int pass = 0; pass < 2; ++pass) {
        const unsigned short* A = pass ? sb : db;
        const unsigned short* B = Wdb + pass * HIDDEN;   // col offset in [512][1024]
        for (int k0 = 0; k0 < HIDDEN; k0 += 32) {
            *(float4*)(As + arow * LDT + aseg * 8) =
                *(const float4*)(A + (size_t)(m0 + arow) * HIDDEN + k0 + aseg * 8);
            if (tid < 128)
                *(float4*)(Bs + arow * LDT + aseg * 8) =
                    *(const float4*)(B + (size_t)(n0 + arow) * (2 * HIDDEN) + k0 + aseg * 8);
            __syncthreads();
            short8 a0 = *(const short8*)(As + (wm * 32 + lr) * LDT + qk);
            short8 a1 = *(const short8*)(As + (wm * 32 + 16 + lr) * LDT + qk);
            short8 b  = *(const short8*)(Bs + (wn * 16 + lr) * LDT + qk);
            acc[0] = mfma16(a0, b, acc[0]);
            acc[1] = mfma16(a1, b, acc[1]);
            __syncthreads();
        }
    }
#pragma unroll
    for (int mf = 0; mf < 2; ++mf) {
        float rs[4];
#pragma unroll
        for (int r = 0; r < 4; ++r) {
            const int b = m0 + wm * 32 + mf * 16 + quad * 4 + r;
            const int i = n0 + wn * 16 + lr;
            float v = tanhf(acc[mf][r] + bf2f(Gtb[(size_t)b * HIDDEN + i])) * vd[i];
            for (int msk = 1; msk < 16; msk <<= 1) v += __shfl_xor(v, msk, 16);
            rs[r] = v;
        }
        if (lr == 0)
#pragma unroll
            for (int r = 0; r < 4; ++r)
                red[wn][wm * 32 + mf * 16 + quad * 4 + r] = rs[r];
    }
    __syncthreads();
    if (tid < 64)
        lpart[(size_t)nb * BATCH + m0 + tid] = red[0][tid] + red[1][tid];
}

// ---------------------------------------------------------------------------
// mid: softmax stats over batch + scalar ct.w recursion:
//   ctw += (sum_b e^{l_b} hw_t[b]) / (sum_b e^{l_b});  yscal = ctw + b00
// ---------------------------------------------------------------------------
__global__ void mid_kernel(const float* __restrict__ lpart, const float* __restrict__ hw_t,
                           float* __restrict__ ctw, const float* __restrict__ b00,
                           float* __restrict__ yscal, const float* __restrict__ yr_dot,
                           float* __restrict__ y_out) {
    __shared__ float sm[1024];
    __shared__ float sm2[1024];
    __shared__ float ysh;
    const int tid = threadIdx.x;  // 1024
    float l0 = 0.f, l1 = 0.f;
#pragma unroll
    for (int p = 0; p < 16; ++p) {
        l0 += lpart[p * BATCH + tid];
        l1 += lpart[p * BATCH + 1024 + tid];
    }
    sm[tid] = fmaxf(l0, l1);
    __syncthreads();
    for (int off = 512; off; off >>= 1) {
        if (tid < off) sm[tid] = fmaxf(sm[tid], sm[tid + off]);
        __syncthreads();
    }
    const float M = sm[0];
    __syncthreads();
    const float e0 = expf(l0 - M), e1 = expf(l1 - M);
    sm[tid]  = e0 + e1;
    sm2[tid] = e0 * hw_t[tid] + e1 * hw_t[1024 + tid];
    __syncthreads();
    for (int off = 512; off; off >>= 1) {
        if (tid < off) { sm[tid] += sm[tid + off]; sm2[tid] += sm2[tid + off]; }
        __syncthreads();
    }
    if (tid == 0) {
        const float c = ctw[0] + sm2[0] / sm[0];
        ctw[0] = c;
        ysh = c + b00[0];
        yscal[0] = ysh;
    }
    __syncthreads();
    if (y_out != nullptr) {
        const float ys = ysh;
        y_out[tid]        = yr_dot[tid] + ys;
        y_out[1024 + tid] = yr_dot[1024 + tid] + ys;
    }
}

// ---------------------------------------------------------------------------
// gates GEMM (4 gates, 64x32 tile each) + fused LSTM update. 512 blocks.
// ---------------------------------------------------------------------------
__global__ __launch_bounds__(256) void gates_lstm_mfma(
        const unsigned short* __restrict__ db, const unsigned short* __restrict__ Whhb,
        const float* __restrict__ Wih, const float* __restrict__ bih,
        const float* __restrict__ bhh, const float* __restrict__ yr_dot,
        const float* __restrict__ yscal, const float* __restrict__ s_old,
        float* __restrict__ s_new, float* __restrict__ d_new,
        unsigned short* __restrict__ sb_new, unsigned short* __restrict__ db_new) {
    __shared__ __align__(16) short As[64 * LDT];
    __shared__ __align__(16) short Bs[4][32 * LDT];
    const int tid = threadIdx.x;
    const int wave = tid >> 6, lane = tid & 63;
    const int wm = wave >> 1, wn = wave & 1;
    const int quad = lane >> 4, lr = lane & 15, qk = quad * 8;
    const int m0 = (blockIdx.x & 31) * 64;
    const int n0 = (blockIdx.x >> 5) * 32;   // 0..15 -> 32-col slices
    const int arow = tid >> 2, aseg = tid & 3;
    floatx4 acc[4][2] = {};
    for (int k0 = 0; k0 < HIDDEN; k0 += 32) {
        *(float4*)(As + arow * LDT + aseg * 8) =
            *(const float4*)(db + (size_t)(m0 + arow) * HIDDEN + k0 + aseg * 8);
#pragma unroll
        for (int j = 0; j < 2; ++j) {
            const int c = tid + 256 * j;         // 512 chunks: 4g x 32row x 4seg
            const int g = c >> 7, cc = c & 127, row = cc >> 2, seg = cc & 3;
            *(float4*)(Bs[g] + row * LDT + seg * 8) =
                *(const float4*)(Whhb + (size_t)(g * HIDDEN + n0 + row) * HIDDEN + k0 + seg * 8);
        }
        __syncthreads();
        short8 a0 = *(const short8*)(As + (wm * 32 + lr) * LDT + qk);
        short8 a1 = *(const short8*)(As + (wm * 32 + 16 + lr) * LDT + qk);
#pragma unroll
        for (int g = 0; g < 4; ++g) {
            short8 b = *(const short8*)(Bs[g] + (wn * 16 + lr) * LDT + qk);
            acc[g][0] = mfma16(a0, b, acc[g][0]);
            acc[g][1] = mfma16(a1, b, acc[g][1]);
        }
        __syncthreads();
    }
    const float ys = yscal[0];
    const int i = n0 + wn * 16 + lr;
    float wi[4], cb[4];
#pragma unroll
    for (int g = 0; g < 4; ++g) {
        wi[g] = Wih[g * HIDDEN + i];
        cb[g] = bih[g * HIDDEN + i] + bhh[g * HIDDEN + i];
    }
#pragma unroll
    for (int mf = 0; mf < 2; ++mf) {
#pragma unroll
        for (int r = 0; r < 4; ++r) {
            const int b = m0 + wm * 32 + mf * 16 + quad * 4 + r;
            const float yf = yr_dot[b] + ys;
            const size_t idx = (size_t)b * HIDDEN + i;
            const float ig = acc[0][mf][r] + yf * wi[0] + cb[0];
            const float fg = acc[1][mf][r] + yf * wi[1] + cb[1];
            const float gg = acc[2][mf][r] + yf * wi[2] + cb[2];
            const float og = acc[3][mf][r] + yf * wi[3] + cb[3];
            const float sn = sigmoidf(fg) * s_old[idx] + sigmoidf(ig) * tanhf(gg);
            const float dn = sigmoidf(og) * tanhf(sn);
            s_new[idx] = sn;
            sb_new[idx] = f2bf(sn);
            db_new[idx] = f2bf(dn);
            if (d_new != nullptr) d_new[idx] = dn;
        }
    }
}

// ---------------------------------------------------------------------------
extern "C" void kernel_launch(void* const* d_in, const int* in_sizes, int n_in,
                              void* d_out, int out_size, void* d_ws, size_t ws_size,
                              hipStream_t stream) {
    const float* Z      = (const float*)d_in[0];
    const float* d_init = (const float*)d_in[1];
    const float* s_init = (const float*)d_in[2];
    const float* y_real = (const float*)d_in[3];
    const float* vd     = (const float*)d_in[4];
    const float* Wd     = (const float*)d_in[5];
    const float* Ud     = (const float*)d_in[6];
    const float* w      = (const float*)d_in[7];
    const float* b00    = (const float*)d_in[8];
    const float* conv_w = (const float*)d_in[9];
    const float* conv_b = (const float*)d_in[10];
    const float* Wih    = (const float*)d_in[11];
    const float* Whh    = (const float*)d_in[12];
    const float* bih    = (const float*)d_in[13];
    const float* bhh    = (const float*)d_in[14];

    float* ws = (float*)d_ws;
    size_t off = 0;
    unsigned short* Htb = (unsigned short*)(ws + off);  off += (size_t)WINDOW * BH / 2;
    unsigned short* Gb  = (unsigned short*)(ws + off);  off += (size_t)WINDOW * BH / 2;
    unsigned short* dbb[2];
    dbb[0] = (unsigned short*)(ws + off);  off += BH / 2;   // BH bf16 elems = BH/2 floats
    dbb[1] = (unsigned short*)(ws + off);  off += BH / 2;
    unsigned short* sbb[2];
    sbb[0] = (unsigned short*)(ws + off);  off += BH / 2;
    sbb[1] = (unsigned short*)(ws + off);  off += BH / 2;
    float* sbuf[2];
    sbuf[0] = ws + off;  off += BH;
    sbuf[1] = ws + off;  off += BH;
    unsigned short* Wdb  = (unsigned short*)(ws + off);  off += (size_t)HIDDEN * 2 * HIDDEN / 2;
    unsigned short* Udb  = (unsigned short*)(ws + off);  off += (size_t)HIDDEN * HIDDEN / 2;
    unsigned short* Whhb = (unsigned short*)(ws + off);  off += (size_t)H4 * HIDDEN / 2;
    float* hw     = ws + off;  off += (size_t)WINDOW * BATCH;
    float* lpart  = ws + off;  off += (size_t)16 * BATCH;
    float* yr_dot = ws + off;  off += BATCH;
    float* ctw    = ws + off;  off += 4;
    float* yscal  = ws + off;  off += 4;

    float* out = (float*)d_out;
    float* y_out   = out;
    float* d_out_f = out + BATCH;
    float* s_out_f = out + BATCH + (size_t)BH;

    // --- one-time prep ---
    cvt5_kernel<<<3840, 256, 0, stream>>>(Wd, Wdb, Ud, Udb, Whh, Whhb,
                                          d_init, dbb[0], s_init, sbb[0]);
    conv_kernel<<<BATCH, 256, 0, stream>>>(Z, conv_w, conv_b, (unsigned int*)Htb);
    hw_kernel<<<(WINDOW * BATCH) / 4, 256, 0, stream>>>(Htb, w, hw);
    {
        dim3 grid((WINDOW * BATCH) / 64, HIDDEN / 64);  // 768 x 8
        g_gemm_mfma<<<grid, 256, 0, stream>>>(Htb, Udb, Gb);
    }
    init_kernel<<<8, 256, 0, stream>>>(y_real, w, yr_dot, ctw);

    // --- scan over 24 steps: 3 launches/step ---
    const float* s_read = s_init;
    int pp = 0;
    for (int t = 0; t < WINDOW; ++t) {
        const unsigned short* Gtb = Gb + (size_t)t * BH;
        s1_mfma<<<512, 256, 0, stream>>>(dbb[pp], sbb[pp], Wdb, Gtb, vd, lpart);
        mid_kernel<<<1, 1024, 0, stream>>>(lpart, hw + t * BATCH, ctw, b00, yscal, yr_dot,
                                           (t == WINDOW - 1) ? y_out : nullptr);
        float* s_w = (t == WINDOW - 1) ? s_out_f : sbuf[t & 1];
        float* d_w = (t == WINDOW - 1) ? d_out_f : nullptr;
        gates_lstm_mfma<<<512, 256, 0, stream>>>(dbb[pp], Whhb, Wih, bih, bhh, yr_dot,
                                                 yscal, s_read, s_w, d_w,
                                                 sbb[1 - pp], dbb[1 - pp]);
        s_read = s_w;
        pp ^= 1;
    }
}